// Round 9
// baseline (28.718 us; speedup 1.0000x reference)
//
#include <hip/hip_runtime.h>
#include <math.h>

#ifndef M_PI
#define M_PI 3.14159265358979323846
#endif

#define MA 768
#define ROWF (3 * MA)   // 2304 floats per row

// Full-wave (64-lane) sum via DPP on the VALU pipe; total lands in lane 63.
__device__ __forceinline__ float dpp_red_add(float v) {
    v += __int_as_float(__builtin_amdgcn_update_dpp(0, __float_as_int(v), 0x111, 0xf, 0xf, true)); // row_shr:1
    v += __int_as_float(__builtin_amdgcn_update_dpp(0, __float_as_int(v), 0x112, 0xf, 0xf, true)); // row_shr:2
    v += __int_as_float(__builtin_amdgcn_update_dpp(0, __float_as_int(v), 0x114, 0xf, 0xe, true)); // row_shr:4
    v += __int_as_float(__builtin_amdgcn_update_dpp(0, __float_as_int(v), 0x118, 0xf, 0xc, true)); // row_shr:8
    v += __int_as_float(__builtin_amdgcn_update_dpp(0, __float_as_int(v), 0x142, 0xa, 0xf, true)); // row_bcast:15
    v += __int_as_float(__builtin_amdgcn_update_dpp(0, __float_as_int(v), 0x143, 0xc, 0xf, true)); // row_bcast:31
    return v;
}

struct Acc {
    float sxp[3], syp[3], cp[3][3], nx2, ny2;
};

// Consume one 256-float chunk K. Lane holds x[p..p+3] (p = 256K + 4*lane)
// and the y-window y[p-2..p+5] as ya/yb. Rotated accumulation: component of
// x[p+e] is (K + r + e) % 3 (r = lane%3); rotated row index m = (K+e)%3 is
// compile-time; y partner selected from the window by r with 2 cndmasks.
template<int K, bool MASK, bool FIRST, bool LAST>
__device__ __forceinline__ void consume(const float4& xr, const float4& ya,
                                        const float4& yb, int pl, int nf,
                                        bool r1, bool r2, bool lane0,
                                        bool lane63, Acc& A)
{
    float yc[8] = {ya.x, ya.y, ya.z, ya.w, yb.x, yb.y, yb.z, yb.w};
    if (FIRST) {   // lane 0's ya was clamped to row start: y[0],y[1] sit in .x,.y
        yc[2] = lane0 ? ya.x : ya.z;
        yc[3] = lane0 ? ya.y : ya.w;
    }
    if (LAST) {    // lane 63's yb was clamped to row end: y[p+2],y[p+3] in .z,.w
        yc[4] = lane63 ? yb.z : yb.x;
        yc[5] = lane63 ? yb.w : yb.y;
    }
    const float xe[4] = {xr.x, xr.y, xr.z, xr.w};
#pragma unroll
    for (int e = 0; e < 4; ++e) {
        float x = xe[e];
        float yal = yc[e + 2];          // aligned y[p+e]
        if (MASK) {
            const bool v = (256 * K + pl + e) < nf;
            x = v ? x : 0.f;
            yal = v ? yal : 0.f;
        }
        const int m = (K + e) % 3;      // rotated component (compile-time)
        A.sxp[m] += x;
        A.syp[m] += yal;
        A.nx2 = fmaf(x, x, A.nx2);
        A.ny2 = fmaf(yal, yal, A.ny2);
#pragma unroll
        for (int j = 0; j < 3; ++j) {
            // y partner index in window: e + 2 - i + j, i = (m + r) % 3
            const int c0 = e + 2 - m + j;
            const int c1 = e + 2 - ((m + 1) % 3) + j;
            const int c2 = e + 2 - ((m + 2) % 3) + j;
            const float yj = r1 ? yc[c1] : (r2 ? yc[c2] : yc[c0]);
            A.cp[m][j] = fmaf(x, yj, A.cp[m][j]);
        }
    }
}

#define LOADK(K, xv, av, bv)                                              \
    {                                                                     \
        const int xo = 256 * (K) + pl;                                    \
        int ao = xo - 2;                                                  \
        if ((K) == 0 && ao < 0) ao = 0;                                   \
        int bo = xo + 2;                                                  \
        if ((K) == 8 && bo > ROWF - 4) bo = ROWF - 4;                     \
        xv = *(const float4*)(X + xo);                                    \
        av = *(const float4*)(Y + ao);                                    \
        bv = *(const float4*)(Y + bo);                                    \
    }

__global__ __launch_bounds__(256, 4) void kabsch_kernel(
    const float* __restrict__ inp, const float* __restrict__ tgt,
    const int* __restrict__ natoms, float* __restrict__ out)
{
    const int wave = threadIdx.x >> 6;
    const int lane = threadIdx.x & 63;
    const int b = blockIdx.x * 4 + wave;
    const int n = natoms[b];
    const int nf = 3 * n;
    const float* __restrict__ X = inp + (size_t)b * ROWF;
    const float* __restrict__ Y = tgt + (size_t)b * ROWF;

    const int pl = 4 * lane;
    const int r = lane % 3;
    const bool r1 = (r == 1), r2 = (r == 2);
    const bool lane0 = (lane == 0), lane63 = (lane == 63);

    Acc A;
#pragma unroll
    for (int m = 0; m < 3; ++m) {
        A.sxp[m] = 0.f; A.syp[m] = 0.f;
#pragma unroll
        for (int j = 0; j < 3; ++j) A.cp[m][j] = 0.f;
    }
    A.nx2 = 0.f; A.ny2 = 0.f;

    // ---- coalesced loads, chunks 0..4 (always valid to load: nf >= 1152) ----
    float4 x0, a0, b0, x1, a1, b1, x2, a2, b2, x3, a3, b3, x4, a4, b4;
    LOADK(0, x0, a0, b0);
    LOADK(1, x1, a1, b1);
    LOADK(2, x2, a2, b2);
    LOADK(3, x3, a3, b3);
    LOADK(4, x4, a4, b4);
    __builtin_amdgcn_sched_barrier(0);

    float4 x5, a5, b5, x6, a6, b6, x7, a7, b7, x8, a8, b8;
    const bool k5 = nf > 1280, k6 = nf > 1536, k7 = nf > 1792, k8 = nf > 2048;

    if (k5) LOADK(5, x5, a5, b5);
    consume<0, false, true, false>(x0, a0, b0, pl, nf, r1, r2, lane0, lane63, A);
    if (k6) LOADK(6, x6, a6, b6);
    consume<1, false, false, false>(x1, a1, b1, pl, nf, r1, r2, lane0, lane63, A);
    if (k7) LOADK(7, x7, a7, b7);
    consume<2, false, false, false>(x2, a2, b2, pl, nf, r1, r2, lane0, lane63, A);
    if (k8) LOADK(8, x8, a8, b8);
    consume<3, false, false, false>(x3, a3, b3, pl, nf, r1, r2, lane0, lane63, A);
    consume<4, true, false, false>(x4, a4, b4, pl, nf, r1, r2, lane0, lane63, A);
    if (k5) consume<5, true, false, false>(x5, a5, b5, pl, nf, r1, r2, lane0, lane63, A);
    if (k6) consume<6, true, false, false>(x6, a6, b6, pl, nf, r1, r2, lane0, lane63, A);
    if (k7) consume<7, true, false, false>(x7, a7, b7, pl, nf, r1, r2, lane0, lane63, A);
    if (k8) consume<8, true, false, true>(x8, a8, b8, pl, nf, r1, r2, lane0, lane63, A);

    // ---- un-rotate per lane: true[i] = rot[(i - r) mod 3] ----
    float sx[3], sy[3], c[3][3];
#pragma unroll
    for (int i = 0; i < 3; ++i) {
        const int q0 = i, q1 = (i + 2) % 3, q2 = (i + 1) % 3;
        sx[i] = r1 ? A.sxp[q1] : (r2 ? A.sxp[q2] : A.sxp[q0]);
        sy[i] = r1 ? A.syp[q1] : (r2 ? A.syp[q2] : A.syp[q0]);
#pragma unroll
        for (int j = 0; j < 3; ++j)
            c[i][j] = r1 ? A.cp[q1][j] : (r2 ? A.cp[q2][j] : A.cp[q0][j]);
    }

    // ---- 64-lane reduce of the 17 sums ----
    const float sx0 = dpp_red_add(sx[0]), sx1 = dpp_red_add(sx[1]), sx2 = dpp_red_add(sx[2]);
    const float sy0 = dpp_red_add(sy[0]), sy1 = dpp_red_add(sy[1]), sy2 = dpp_red_add(sy[2]);
    const float c00 = dpp_red_add(c[0][0]), c01 = dpp_red_add(c[0][1]), c02 = dpp_red_add(c[0][2]);
    const float c10 = dpp_red_add(c[1][0]), c11 = dpp_red_add(c[1][1]), c12 = dpp_red_add(c[1][2]);
    const float c20 = dpp_red_add(c[2][0]), c21 = dpp_red_add(c[2][1]), c22 = dpp_red_add(c[2][2]);
    const float nx2 = dpp_red_add(A.nx2), ny2 = dpp_red_add(A.ny2);

    // ---- fused epilogue on lane 63 (f64 products, f32 trig) ----
    if (lane63) {
        const double inv_n = 1.0 / (double)n;

        double R00 = (double)c00 - (double)sx0 * (double)sy0 * inv_n;
        double R01 = (double)c01 - (double)sx0 * (double)sy1 * inv_n;
        double R02 = (double)c02 - (double)sx0 * (double)sy2 * inv_n;
        double R10 = (double)c10 - (double)sx1 * (double)sy0 * inv_n;
        double R11 = (double)c11 - (double)sx1 * (double)sy1 * inv_n;
        double R12 = (double)c12 - (double)sx1 * (double)sy2 * inv_n;
        double R20 = (double)c20 - (double)sx2 * (double)sy0 * inv_n;
        double R21 = (double)c21 - (double)sx2 * (double)sy1 * inv_n;
        double R22 = (double)c22 - (double)sx2 * (double)sy2 * inv_n;
        double ex = (double)nx2 -
            ((double)sx0 * sx0 + (double)sx1 * sx1 + (double)sx2 * sx2) * inv_n;
        double ey = (double)ny2 -
            ((double)sy0 * sy0 + (double)sy1 * sy1 + (double)sy2 * sy2) * inv_n;

        double A00 = R00 * R00 + R10 * R10 + R20 * R20;
        double A11 = R01 * R01 + R11 * R11 + R21 * R21;
        double A22 = R02 * R02 + R12 * R12 + R22 * R22;
        double A01 = R00 * R01 + R10 * R11 + R20 * R21;
        double A02 = R00 * R02 + R10 * R12 + R20 * R22;
        double A12 = R01 * R02 + R11 * R12 + R21 * R22;

        double detR = R00 * (R11 * R22 - R12 * R21)
                    - R01 * (R10 * R22 - R12 * R20)
                    + R02 * (R10 * R21 - R11 * R20);

        double q = (A00 + A11 + A22) / 3.0;
        double p1 = A01 * A01 + A02 * A02 + A12 * A12;
        double b00 = A00 - q, b11 = A11 - q, b22 = A22 - q;
        double p2 = b00 * b00 + b11 * b11 + b22 * b22 + 2.0 * p1;
        double e0, e1, e2;
        if (p2 <= 0.0) {
            e0 = e1 = e2 = q;
        } else {
            double p = sqrt(p2 / 6.0);
            double ip = 1.0 / p;
            double B00 = b00 * ip, B11 = b11 * ip, B22 = b22 * ip;
            double B01 = A01 * ip, B02 = A02 * ip, B12 = A12 * ip;
            double detB = B00 * (B11 * B22 - B12 * B12)
                        - B01 * (B01 * B22 - B12 * B02)
                        + B02 * (B01 * B12 - B11 * B02);
            double rr = 0.5 * detB;
            rr = fmin(1.0, fmax(-1.0, rr));
            float phi = acosf((float)rr) * (1.0f / 3.0f);
            float cA = __cosf(phi);
            float cC = __cosf(phi + (float)(2.0 * M_PI / 3.0));
            e0 = q + 2.0 * p * (double)cA;
            e2 = q + 2.0 * p * (double)cC;
            e1 = 3.0 * q - e0 - e2;
        }
        double s0 = sqrt(fmax(e0, 0.0));
        double s1 = sqrt(fmax(e1, 0.0));
        double s2 = sqrt(fmax(e2, 0.0));
        double d = (detR > 0.0) ? 1.0 : ((detR < 0.0) ? -1.0 : 0.0);
        double tr = s0 + s1 + d * s2;
        double e = ex + ey - 2.0 * tr;
        out[b] = (float)sqrt(fmax(e, 0.0) * inv_n + 1e-7);
    }
}

extern "C" void kernel_launch(void* const* d_in, const int* in_sizes, int n_in,
                              void* d_out, int out_size, void* d_ws, size_t ws_size,
                              hipStream_t stream) {
    const float* inp = (const float*)d_in[0];
    const float* tgt = (const float*)d_in[1];
    const int* natoms = (const int*)d_in[2];
    float* out = (float*)d_out;
    (void)d_ws; (void)ws_size; (void)n_in; (void)in_sizes;
    kabsch_kernel<<<dim3(out_size / 4), dim3(256), 0, stream>>>(inp, tgt, natoms, out);
}

// Round 10
// 24.516 us; speedup vs baseline: 1.1714x; 1.1714x over previous
//
#include <hip/hip_runtime.h>
#include <math.h>

#ifndef M_PI
#define M_PI 3.14159265358979323846
#endif

#define MA 768   // MAX_ATOMS

// Full-wave (64-lane) sum via DPP on the VALU pipe; total lands in lane 63.
__device__ __forceinline__ float dpp_red_add(float v) {
    v += __int_as_float(__builtin_amdgcn_update_dpp(0, __float_as_int(v), 0x111, 0xf, 0xf, true)); // row_shr:1
    v += __int_as_float(__builtin_amdgcn_update_dpp(0, __float_as_int(v), 0x112, 0xf, 0xf, true)); // row_shr:2
    v += __int_as_float(__builtin_amdgcn_update_dpp(0, __float_as_int(v), 0x114, 0xf, 0xe, true)); // row_shr:4
    v += __int_as_float(__builtin_amdgcn_update_dpp(0, __float_as_int(v), 0x118, 0xf, 0xc, true)); // row_shr:8
    v += __int_as_float(__builtin_amdgcn_update_dpp(0, __float_as_int(v), 0x142, 0xa, 0xf, true)); // row_bcast:15
    v += __int_as_float(__builtin_amdgcn_update_dpp(0, __float_as_int(v), 0x143, 0xc, 0xf, true)); // row_bcast:31
    return v;
}

// ONE kernel, ONE WAVE PER SAMPLE, register path (no LDS) — R8 structure.
// 12 atoms/lane; 18 dwordx4 loads in one exec-masked cluster, pinned by
// sched_barrier(0). DPP-reduce 17 sums; lane 63 runs an ALL-F32 eigensolve
// (threshold 5e-2; f32 epilogue error ~1e-4) and writes out.
__global__ __launch_bounds__(256, 4) void kabsch_kernel(
    const float* __restrict__ inp, const float* __restrict__ tgt,
    const int* __restrict__ natoms, float* __restrict__ out)
{
    const int wave = threadIdx.x >> 6;
    const int lane = threadIdx.x & 63;
    const int b = blockIdx.x * 4 + wave;
    const int n = natoms[b];
    const float* __restrict__ X = inp + (size_t)b * (3 * MA);
    const float* __restrict__ Y = tgt + (size_t)b * (3 * MA);

    const int a0 = 12 * lane;  // this lane's first atom

    const float4 f4z = make_float4(0.f, 0.f, 0.f, 0.f);
    float4 vx[9], vy[9];
#pragma unroll
    for (int k = 0; k < 9; ++k) { vx[k] = f4z; vy[k] = f4z; }

    if (a0 < n) {  // exec-masked: lanes fully in the invalid tail fetch nothing
        const float4* px = (const float4*)(X + 3 * a0);
        const float4* py = (const float4*)(Y + 3 * a0);
#pragma unroll
        for (int k = 0; k < 9; ++k) vx[k] = px[k];
#pragma unroll
        for (int k = 0; k < 9; ++k) vy[k] = py[k];
    }
    __builtin_amdgcn_sched_barrier(0);  // all loads issue before any consume

    float ax[36], ay[36];
#pragma unroll
    for (int k = 0; k < 9; ++k) {
        *(float4*)&ax[4 * k] = vx[k];
        *(float4*)&ay[4 * k] = vy[k];
    }

    float sx0 = 0.f, sx1 = 0.f, sx2 = 0.f;
    float sy0 = 0.f, sy1 = 0.f, sy2 = 0.f;
    float c00 = 0.f, c01 = 0.f, c02 = 0.f;
    float c10 = 0.f, c11 = 0.f, c12 = 0.f;
    float c20 = 0.f, c21 = 0.f, c22 = 0.f;
    float nx2 = 0.f, ny2 = 0.f;

#pragma unroll
    for (int j = 0; j < 12; ++j) {
        const bool v = (a0 + j) < n;
        const float x0 = v ? ax[3 * j + 0] : 0.f;
        const float x1 = v ? ax[3 * j + 1] : 0.f;
        const float x2 = v ? ax[3 * j + 2] : 0.f;
        const float y0 = v ? ay[3 * j + 0] : 0.f;
        const float y1 = v ? ay[3 * j + 1] : 0.f;
        const float y2 = v ? ay[3 * j + 2] : 0.f;
        sx0 += x0; sx1 += x1; sx2 += x2;
        sy0 += y0; sy1 += y1; sy2 += y2;
        c00 = fmaf(x0, y0, c00); c01 = fmaf(x0, y1, c01); c02 = fmaf(x0, y2, c02);
        c10 = fmaf(x1, y0, c10); c11 = fmaf(x1, y1, c11); c12 = fmaf(x1, y2, c12);
        c20 = fmaf(x2, y0, c20); c21 = fmaf(x2, y1, c21); c22 = fmaf(x2, y2, c22);
        nx2 = fmaf(x0, x0, nx2); nx2 = fmaf(x1, x1, nx2); nx2 = fmaf(x2, x2, nx2);
        ny2 = fmaf(y0, y0, ny2); ny2 = fmaf(y1, y1, ny2); ny2 = fmaf(y2, y2, ny2);
    }

    sx0 = dpp_red_add(sx0); sx1 = dpp_red_add(sx1); sx2 = dpp_red_add(sx2);
    sy0 = dpp_red_add(sy0); sy1 = dpp_red_add(sy1); sy2 = dpp_red_add(sy2);
    c00 = dpp_red_add(c00); c01 = dpp_red_add(c01); c02 = dpp_red_add(c02);
    c10 = dpp_red_add(c10); c11 = dpp_red_add(c11); c12 = dpp_red_add(c12);
    c20 = dpp_red_add(c20); c21 = dpp_red_add(c21); c22 = dpp_red_add(c22);
    nx2 = dpp_red_add(nx2); ny2 = dpp_red_add(ny2);

    // Fused epilogue on lane 63 — ALL F32 (output threshold 5e-2; this
    // path's absolute error is ~1e-4).
    if (lane == 63) {
        const float inv_n = 1.0f / (float)n;

        const float R00 = fmaf(-sx0 * inv_n, sy0, c00);
        const float R01 = fmaf(-sx0 * inv_n, sy1, c01);
        const float R02 = fmaf(-sx0 * inv_n, sy2, c02);
        const float R10 = fmaf(-sx1 * inv_n, sy0, c10);
        const float R11 = fmaf(-sx1 * inv_n, sy1, c11);
        const float R12 = fmaf(-sx1 * inv_n, sy2, c12);
        const float R20 = fmaf(-sx2 * inv_n, sy0, c20);
        const float R21 = fmaf(-sx2 * inv_n, sy1, c21);
        const float R22 = fmaf(-sx2 * inv_n, sy2, c22);
        const float ex = nx2 - (sx0 * sx0 + sx1 * sx1 + sx2 * sx2) * inv_n;
        const float ey = ny2 - (sy0 * sy0 + sy1 * sy1 + sy2 * sy2) * inv_n;

        // A = R^T R (symmetric PSD); eigenvalues are squared singular values
        const float A00 = R00 * R00 + R10 * R10 + R20 * R20;
        const float A11 = R01 * R01 + R11 * R11 + R21 * R21;
        const float A22 = R02 * R02 + R12 * R12 + R22 * R22;
        const float A01 = R00 * R01 + R10 * R11 + R20 * R21;
        const float A02 = R00 * R02 + R10 * R12 + R20 * R22;
        const float A12 = R01 * R02 + R11 * R12 + R21 * R22;

        const float detR = R00 * (R11 * R22 - R12 * R21)
                         - R01 * (R10 * R22 - R12 * R20)
                         + R02 * (R10 * R21 - R11 * R20);

        const float q = (A00 + A11 + A22) * (1.0f / 3.0f);
        const float p1 = A01 * A01 + A02 * A02 + A12 * A12;
        const float b00 = A00 - q, b11 = A11 - q, b22 = A22 - q;
        const float p2 = b00 * b00 + b11 * b11 + b22 * b22 + 2.0f * p1;
        float e0, e1, e2;
        if (p2 <= 0.0f) {
            e0 = e1 = e2 = q;
        } else {
            const float p = sqrtf(p2 * (1.0f / 6.0f));
            const float ip = 1.0f / p;
            const float B00 = b00 * ip, B11 = b11 * ip, B22 = b22 * ip;
            const float B01 = A01 * ip, B02 = A02 * ip, B12 = A12 * ip;
            const float detB = B00 * (B11 * B22 - B12 * B12)
                             - B01 * (B01 * B22 - B12 * B02)
                             + B02 * (B01 * B12 - B11 * B02);
            float rr = 0.5f * detB;
            rr = fminf(1.0f, fmaxf(-1.0f, rr));
            const float phi = acosf(rr) * (1.0f / 3.0f);
            const float cA = __cosf(phi);
            const float cC = __cosf(phi + (float)(2.0 * M_PI / 3.0));
            e0 = fmaf(2.0f * p, cA, q);
            e2 = fmaf(2.0f * p, cC, q);
            e1 = 3.0f * q - e0 - e2;
        }
        const float s0 = sqrtf(fmaxf(e0, 0.0f));
        const float s1 = sqrtf(fmaxf(e1, 0.0f));
        const float s2 = sqrtf(fmaxf(e2, 0.0f));
        const float d = (detR > 0.0f) ? 1.0f : ((detR < 0.0f) ? -1.0f : 0.0f);
        const float tr = s0 + s1 + d * s2;
        const float e = ex + ey - 2.0f * tr;
        out[b] = sqrtf(fmaxf(e, 0.0f) * inv_n + 1e-7f);
    }
}

extern "C" void kernel_launch(void* const* d_in, const int* in_sizes, int n_in,
                              void* d_out, int out_size, void* d_ws, size_t ws_size,
                              hipStream_t stream) {
    const float* inp = (const float*)d_in[0];
    const float* tgt = (const float*)d_in[1];
    const int* natoms = (const int*)d_in[2];
    float* out = (float*)d_out;
    (void)d_ws; (void)ws_size; (void)n_in; (void)in_sizes;
    kabsch_kernel<<<dim3(out_size / 4), dim3(256), 0, stream>>>(inp, tgt, natoms, out);
}